// Round 1
// baseline (336.522 us; speedup 1.0000x reference)
//
#include <hip/hip_runtime.h>

#define B_    32
#define C_    512
#define HW2_  1024
#define NW    77
#define NP    80
#define WD    256

// ---------------------------------------------------------------------------
// Kernel 1: we[b,n,k] = word_emb[b,n,:] . W_fc[k,:] + b_fc[k]
// Per-batch GEMM: M=77(->80), N=128 k-cols per block, K=256.
// grid (32, 8), 256 threads. Register tile 5n x 8k per thread.
// ---------------------------------------------------------------------------
__global__ __launch_bounds__(256) void we_gemm(
    const float* __restrict__ word_emb, const float* __restrict__ W_fc,
    const float* __restrict__ b_fc, float* __restrict__ we)
{
    __shared__ float A[NP][36];    // n x d-tile (stride 36: 16B-aligned cols, bank phase 4)
    __shared__ float Wt[128][36];  // k x d-tile

    const int t  = threadIdx.x;
    const int b  = blockIdx.x;
    const int k0 = blockIdx.y * 128;
    const int kg = t & 15;     // k = k0 + kg + 16*j  (j<8) -> coalesced stores
    const int ng = t >> 4;     // n = 5*ng + i        (i<5)

    float acc[5][8];
    #pragma unroll
    for (int i = 0; i < 5; ++i)
        #pragma unroll
        for (int j = 0; j < 8; ++j) acc[i][j] = 0.f;

    for (int dt = 0; dt < 8; ++dt) {
        const int d0 = dt * 32;
        // stage A: 80 rows x 32 cols = 640 float4
        for (int v = t; v < 640; v += 256) {
            const int row = v >> 3, c4 = (v & 7) << 2;
            float4 val = make_float4(0.f, 0.f, 0.f, 0.f);
            if (row < NW)
                val = *(const float4*)&word_emb[(b * NW + row) * WD + d0 + c4];
            *(float4*)&A[row][c4] = val;
        }
        // stage W: 128 rows x 32 cols = 1024 float4
        for (int v = t; v < 1024; v += 256) {
            const int row = v >> 3, c4 = (v & 7) << 2;
            *(float4*)&Wt[row][c4] = *(const float4*)&W_fc[(k0 + row) * WD + d0 + c4];
        }
        __syncthreads();
        #pragma unroll
        for (int dd = 0; dd < 32; dd += 4) {
            float4 a4[5], w4[8];
            #pragma unroll
            for (int i = 0; i < 5; ++i) a4[i] = *(const float4*)&A[5 * ng + i][dd];
            #pragma unroll
            for (int j = 0; j < 8; ++j) w4[j] = *(const float4*)&Wt[kg + 16 * j][dd];
            #pragma unroll
            for (int i = 0; i < 5; ++i)
                #pragma unroll
                for (int j = 0; j < 8; ++j)
                    acc[i][j] += a4[i].x * w4[j].x + a4[i].y * w4[j].y
                               + a4[i].z * w4[j].z + a4[i].w * w4[j].w;
        }
        __syncthreads();
    }

    #pragma unroll
    for (int j = 0; j < 8; ++j) {
        const int k = k0 + kg + 16 * j;
        const float bias = b_fc[k];
        #pragma unroll
        for (int i = 0; i < 5; ++i) {
            const int n = 5 * ng + i;
            if (n < NW) we[(b * NW + n) * HW2_ + k] = acc[i][j] + bias;
        }
    }
}

// ---------------------------------------------------------------------------
// Kernel 2: fused scores -> softmax -> out, per (b, 64-row c-tile).
// grid 256 = 32 b x 8 ctiles, 256 threads.
// ---------------------------------------------------------------------------
__global__ __launch_bounds__(256) void attn_fused(
    const float* __restrict__ feat, const float* __restrict__ we,
    float* __restrict__ out)
{
    __shared__ float f_lds[64][68];   // c x k-tile
    __shared__ float we_lds[NP][68];  // n x k-tile (rows 77..79 zeroed)
    __shared__ float att[64][84];     // c x n (scores -> exp; cols 77..79 zeroed)
    __shared__ float red[64][4];
    __shared__ float rowmax[64];
    __shared__ float rowinv[64];

    const int t  = threadIdx.x;
    const int b  = blockIdx.x >> 3;
    const int c0 = (blockIdx.x & 7) * 64;
    const float* fb  = feat + (b * C_ + c0) * HW2_;
    const float* web = we + b * NW * HW2_;

    const int cg = t >> 4;   // c = 4*cg + i
    const int ng = t & 15;   // n = 5*ng + j

    // ---------------- Phase 1: scores[c][n] = sum_k f[c][k]*we[n][k] ----------
    float acc[4][5];
    #pragma unroll
    for (int i = 0; i < 4; ++i)
        #pragma unroll
        for (int j = 0; j < 5; ++j) acc[i][j] = 0.f;

    for (int kt = 0; kt < 16; ++kt) {
        const int k0 = kt * 64;
        #pragma unroll
        for (int r = 0; r < 4; ++r) {   // f: 1024 float4
            const int v = t + 256 * r;
            const int row = v >> 4, c4 = (v & 15) << 2;
            *(float4*)&f_lds[row][c4] = *(const float4*)&fb[row * HW2_ + k0 + c4];
        }
        #pragma unroll
        for (int r = 0; r < 5; ++r) {   // we: 1280 float4
            const int v = t + 256 * r;
            const int row = v >> 4, c4 = (v & 15) << 2;
            float4 val = make_float4(0.f, 0.f, 0.f, 0.f);
            if (row < NW) val = *(const float4*)&web[row * HW2_ + k0 + c4];
            *(float4*)&we_lds[row][c4] = val;
        }
        __syncthreads();
        #pragma unroll
        for (int kk = 0; kk < 64; kk += 4) {
            float4 a4[4], w4[5];
            #pragma unroll
            for (int i = 0; i < 4; ++i) a4[i] = *(const float4*)&f_lds[4 * cg + i][kk];
            #pragma unroll
            for (int j = 0; j < 5; ++j) w4[j] = *(const float4*)&we_lds[5 * ng + j][kk];
            #pragma unroll
            for (int i = 0; i < 4; ++i)
                #pragma unroll
                for (int j = 0; j < 5; ++j)
                    acc[i][j] += a4[i].x * w4[j].x + a4[i].y * w4[j].y
                               + a4[i].z * w4[j].z + a4[i].w * w4[j].w;
        }
        __syncthreads();
    }

    // ---------------- Phase 2: softmax over n ---------------------------------
    #pragma unroll
    for (int i = 0; i < 4; ++i)
        #pragma unroll
        for (int j = 0; j < 5; ++j) {
            const int n = 5 * ng + j;
            if (n < NW) att[4 * cg + i][n] = acc[i][j];
        }
    if (t < 64) { att[t][77] = 0.f; att[t][78] = 0.f; att[t][79] = 0.f; }
    __syncthreads();

    {
        const int r = t & 63, g = t >> 6;
        float m = -1e30f;
        for (int n = g; n < NW; n += 4) m = fmaxf(m, att[r][n]);
        red[r][g] = m;
        __syncthreads();
        if (t < 64)
            rowmax[t] = fmaxf(fmaxf(red[t][0], red[t][1]), fmaxf(red[t][2], red[t][3]));
        __syncthreads();
        const float rm = rowmax[r];
        float s = 0.f;
        for (int n = g; n < NW; n += 4) {
            const float e = __expf(att[r][n] - rm);
            att[r][n] = e;
            s += e;
        }
        red[r][g] = s;
        __syncthreads();
        if (t < 64)
            rowinv[t] = 1.0f / (red[t][0] + red[t][1] + red[t][2] + red[t][3]);
        __syncthreads();
    }

    // ---------------- Phase 3: out[c][k] = (sum_n e[c][n]*we[n][k]) * inv[c] --
    const int kg = t & 15;   // k = 4*kg within tile (float4 of k)
    float inv[4];
    #pragma unroll
    for (int i = 0; i < 4; ++i) inv[i] = rowinv[4 * cg + i];
    float* ob = out + (b * C_ + c0) * HW2_;

    for (int kt = 0; kt < 16; ++kt) {
        const int k0 = kt * 64;
        __syncthreads();   // previous tile's we_lds readers done
        #pragma unroll
        for (int r = 0; r < 5; ++r) {
            const int v = t + 256 * r;
            const int row = v >> 4, c4 = (v & 15) << 2;
            float4 val = make_float4(0.f, 0.f, 0.f, 0.f);
            if (row < NW) val = *(const float4*)&web[row * HW2_ + k0 + c4];
            *(float4*)&we_lds[row][c4] = val;
        }
        __syncthreads();

        float4 o[4];
        #pragma unroll
        for (int i = 0; i < 4; ++i) o[i] = make_float4(0.f, 0.f, 0.f, 0.f);

        #pragma unroll
        for (int n4 = 0; n4 < NP; n4 += 4) {
            float4 a4[4];
            #pragma unroll
            for (int i = 0; i < 4; ++i) a4[i] = *(const float4*)&att[4 * cg + i][n4];
            #pragma unroll
            for (int jj = 0; jj < 4; ++jj) {
                const float4 w = *(const float4*)&we_lds[n4 + jj][4 * kg];
                #pragma unroll
                for (int i = 0; i < 4; ++i) {
                    const float a = ((const float*)&a4[i])[jj];
                    o[i].x += a * w.x; o[i].y += a * w.y;
                    o[i].z += a * w.z; o[i].w += a * w.w;
                }
            }
        }
        #pragma unroll
        for (int i = 0; i < 4; ++i) {
            float4 v = o[i];
            v.x *= inv[i]; v.y *= inv[i]; v.z *= inv[i]; v.w *= inv[i];
            *(float4*)&ob[(4 * cg + i) * HW2_ + k0 + 4 * kg] = v;
        }
    }
}

// ---------------------------------------------------------------------------
extern "C" void kernel_launch(void* const* d_in, const int* in_sizes, int n_in,
                              void* d_out, int out_size, void* d_ws, size_t ws_size,
                              hipStream_t stream) {
    const float* feat     = (const float*)d_in[0];
    const float* word_emb = (const float*)d_in[1];
    const float* W_fc     = (const float*)d_in[2];
    const float* b_fc     = (const float*)d_in[3];
    float* out = (float*)d_out;
    float* we  = (float*)d_ws;   // 32*77*1024 floats = 10.1 MB scratch

    dim3 g1(32, 8);
    we_gemm<<<g1, 256, 0, stream>>>(word_emb, W_fc, b_fc, we);
    attn_fused<<<256, 256, 0, stream>>>(feat, we, out);
}